// Round 1
// baseline (1003.357 us; speedup 1.0000x reference)
//
#include <hip/hip_runtime.h>
#include <hip/hip_bf16.h>

typedef float f32x4 __attribute__((ext_vector_type(4)));
typedef __bf16 bf16x8 __attribute__((ext_vector_type(8)));
typedef unsigned short u16x4 __attribute__((ext_vector_type(4)));
typedef unsigned short u16x8 __attribute__((ext_vector_type(8)));

// LDS layout (bytes). Total 75776 -> 2 blocks/CU (160K LDS).
#define SA   0          // 24576 : [64][192] bf16, row stride 384B, XOR-swizzled. h / projout / h2 / mlpout
#define SQ   24576      // 8192  : [64][64] bf16, stride 128B, swizzled
#define SK   32768      // 8192
#define SVT  40960      // 8192  : V^T per pair: row = d (0..63), col = token
#define SG   24576      // overlays SQ+SK+SVT: [64][192] bf16 gelu chunk (MLP phase)
#define SP   49152      // 16384 : 2 heads x [64][64] bf16 softmax probs
#define SO   65536      // 8192  : O pair [64][64] bf16
#define RED  73728      // 2048  : float[256][2] LN partials
#define SMEM_BYTES 75776

__device__ __forceinline__ int swzA(int row, int cb){ return row*384 + (cb ^ ((row&7)<<4)); }
__device__ __forceinline__ int swz64(int row, int cb){ return row*128 + (cb ^ ((row&7)<<4)); }
__device__ __forceinline__ unsigned short f2b(float x){ return __builtin_bit_cast(unsigned short, (__bf16)x); }
__device__ __forceinline__ float b2f(unsigned short u){ return (float)__builtin_bit_cast(__bf16, u); }

// Transpose + cast weights to bf16 [N][K] so MFMA B-fragments are 8 contiguous elems.
__global__ void prep_weights(const float* __restrict__ wqkv, const float* __restrict__ wproj,
                             const float* __restrict__ wmlp1, const float* __restrict__ wmlp2,
                             unsigned short* __restrict__ ws){
  int idx = blockIdx.x*256 + threadIdx.x;
  if (idx < 110592){ int n=idx/192, k=idx%192; ws[idx] = f2b(wqkv[k*576+n]); }
  else if (idx < 147456){ int i=idx-110592; int n=i/192, k=i%192; ws[idx] = f2b(wproj[k*192+n]); }
  else if (idx < 294912){ int i=idx-147456; int n=i/192, k=i%192; ws[idx] = f2b(wmlp1[k*768+n]); }
  else if (idx < 442368){ int i=idx-294912; int n=i/768, k=i%768; ws[idx] = f2b(wmlp2[k*192+n]); }
}

__global__ void __launch_bounds__(256, 2) winblock(
    const float* __restrict__ x,
    const float* __restrict__ bqkv, const float* __restrict__ bproj,
    const float* __restrict__ ln1g, const float* __restrict__ ln1b,
    const float* __restrict__ ln2g, const float* __restrict__ ln2b,
    const float* __restrict__ bmlp1, const float* __restrict__ bmlp2,
    const unsigned short* __restrict__ wqkvT, const unsigned short* __restrict__ wprojT,
    const unsigned short* __restrict__ wmlp1T, const unsigned short* __restrict__ wmlp2T,
    float* __restrict__ out)
{
  __shared__ __align__(16) char sm[SMEM_BYTES];
  const int tid=threadIdx.x, w=tid>>6, l=tid&63, l16=l&15, lg=l>>4;
  const int wid=blockIdx.x, bb=wid>>10, wh=(wid>>5)&31, wwi=wid&31;
  const size_t imgoff=(size_t)bb*192*65536 + (size_t)(wh*8)*256 + (size_t)(wwi*8);
  const int toff=(l>>3)*256 + (l&7);   // this thread's token = l
  float* red=(float*)(sm+RED);

  // ---- Phase A: load x window. t[i] = residual, channel w*48+i, token l (f32, registers) ----
  float t[48];
  #pragma unroll
  for(int i=0;i<48;++i) t[i]=x[imgoff+(size_t)(w*48+i)*65536+(size_t)toff];

  // ---- Phase B: LN1 -> sA (bf16 h) ----
  {
    float s=0.f,s2=0.f;
    #pragma unroll
    for(int i=0;i<48;++i){ s+=t[i]; s2+=t[i]*t[i]; }
    red[(w*64+l)*2]=s; red[(w*64+l)*2+1]=s2;
    __syncthreads();
    float S=0.f,S2=0.f;
    #pragma unroll
    for(int u=0;u<4;++u){ S+=red[(u*64+l)*2]; S2+=red[(u*64+l)*2+1]; }
    float mean=S*(1.f/192.f), var=S2*(1.f/192.f)-mean*mean, rstd=rsqrtf(var+1e-5f);
    #pragma unroll
    for(int ch=0;ch<6;++ch){
      u16x8 pk;
      #pragma unroll
      for(int j=0;j<8;++j){ int c=w*48+ch*8+j; pk[j]=f2b((t[ch*8+j]-mean)*rstd*ln1g[c]+ln1b[c]); }
      *(u16x8*)(sm+SA+swzA(l, w*96+ch*16))=pk;
    }
    __syncthreads();
  }

  // persistent proj accumulator: wave w owns output cols [48w,48w+48): 4 row-tiles x 3 col-tiles
  f32x4 accP[4][3];
  #pragma unroll
  for(int ii=0;ii<4;++ii){
    #pragma unroll
    for(int jj=0;jj<3;++jj) accP[ii][jj]=(f32x4){0.f,0.f,0.f,0.f};
  }

  const int hl=w>>1, wr=w&1;  // attention: waves 0,1 -> even head of pair; 2,3 -> odd head
  #pragma unroll 1
  for(int p=0;p<3;++p){
    // ---- C.1: QKV for head pair p. Wave w owns tile-cols 3w..3w+2 of [Q|K|V] (12 tile-cols) ----
    {
      f32x4 acc[12];
      #pragma unroll
      for(int i=0;i<12;++i) acc[i]=(f32x4){0.f,0.f,0.f,0.f};
      #pragma unroll
      for(int ks=0;ks<6;++ks){
        bf16x8 a[4];
        #pragma unroll
        for(int tr=0;tr<4;++tr) a[tr]=*(const bf16x8*)(sm+SA+swzA(tr*16+l16, ks*64+lg*16));
        #pragma unroll
        for(int i=0;i<3;++i){
          const int tci=w*3+i, m=tci>>2, tc=tci&3;
          const bf16x8 bw=*(const bf16x8*)(wqkvT + (m*192+p*64+tc*16+l16)*192 + ks*32+lg*8);
          #pragma unroll
          for(int tr=0;tr<4;++tr)
            acc[tr*3+i]=__builtin_amdgcn_mfma_f32_16x16x32_bf16(a[tr],bw,acc[tr*3+i],0,0,0);
        }
      }
      #pragma unroll
      for(int i=0;i<3;++i){
        const int tci=w*3+i, m=tci>>2, tc=tci&3;
        const float bq=bqkv[m*192+p*64+tc*16+l16];
        if(m<2){
          const int base = m?SK:SQ;
          #pragma unroll
          for(int tr=0;tr<4;++tr){
            #pragma unroll
            for(int r=0;r<4;++r)
              *(unsigned short*)(sm+base+swz64(tr*16+lg*4+r,(tc*16+l16)*2))=f2b(acc[tr*3+i][r]+bq);
          }
        } else { // V stored transposed: row = d-in-pair (tc*16+l16), col = token
          #pragma unroll
          for(int tr=0;tr<4;++tr){
            u16x4 pk;
            #pragma unroll
            for(int r=0;r<4;++r) pk[r]=f2b(acc[tr*3+i][r]+bq);
            *(u16x4*)(sm+SVT+swz64(tc*16+l16,(tr*16+lg*4)*2))=pk;
          }
        }
      }
    }
    __syncthreads();
    // ---- C.2: S = Q K^T * scale, softmax -> P (bf16). 2 waves per head, 32 rows each ----
    {
      bf16x8 bk[4];
      #pragma unroll
      for(int tc=0;tc<4;++tc) bk[tc]=*(const bf16x8*)(sm+SK+swz64(tc*16+l16, hl*64+lg*16));
      f32x4 sv[2][4];
      #pragma unroll
      for(int tr=0;tr<2;++tr){
        const bf16x8 aq=*(const bf16x8*)(sm+SQ+swz64(wr*32+tr*16+l16, hl*64+lg*16));
        #pragma unroll
        for(int tc=0;tc<4;++tc)
          sv[tr][tc]=__builtin_amdgcn_mfma_f32_16x16x32_bf16(aq,bk[tc],(f32x4){0.f,0.f,0.f,0.f},0,0,0);
      }
      const float scale=0.17677669529663687f; // 1/sqrt(32)
      #pragma unroll
      for(int tr=0;tr<2;++tr){
        #pragma unroll
        for(int r=0;r<4;++r){
          float mx=-3.0e38f;
          #pragma unroll
          for(int tc=0;tc<4;++tc) mx=fmaxf(mx,sv[tr][tc][r]);
          #pragma unroll
          for(int off=8;off;off>>=1) mx=fmaxf(mx,__shfl_xor(mx,off,16));
          float sum=0.f;
          #pragma unroll
          for(int tc=0;tc<4;++tc){ float e=__expf((sv[tr][tc][r]-mx)*scale); sv[tr][tc][r]=e; sum+=e; }
          #pragma unroll
          for(int off=8;off;off>>=1) sum+=__shfl_xor(sum,off,16);
          const float rs=1.f/sum;
          #pragma unroll
          for(int tc=0;tc<4;++tc) sv[tr][tc][r]*=rs;
        }
      }
      #pragma unroll
      for(int tr=0;tr<2;++tr){
        #pragma unroll
        for(int tc=0;tc<4;++tc){
          #pragma unroll
          for(int r=0;r<4;++r)
            *(unsigned short*)(sm+SP+hl*8192+swz64(wr*32+tr*16+lg*4+r,(tc*16+l16)*2))=f2b(sv[tr][tc][r]);
        }
      }
    }
    __syncthreads();
    // ---- C.3: O = P @ V (per head; B-fragments from V^T are contiguous tokens) ----
    {
      f32x4 ov[2][2];
      #pragma unroll
      for(int ii=0;ii<2;++ii){
        #pragma unroll
        for(int jj=0;jj<2;++jj) ov[ii][jj]=(f32x4){0.f,0.f,0.f,0.f};
      }
      #pragma unroll
      for(int ks=0;ks<2;++ks){
        bf16x8 ap[2];
        #pragma unroll
        for(int tr=0;tr<2;++tr) ap[tr]=*(const bf16x8*)(sm+SP+hl*8192+swz64(wr*32+tr*16+l16, ks*64+lg*16));
        #pragma unroll
        for(int tc=0;tc<2;++tc){
          const bf16x8 bv=*(const bf16x8*)(sm+SVT+swz64(hl*32+tc*16+l16, ks*64+lg*16));
          #pragma unroll
          for(int tr=0;tr<2;++tr)
            ov[tr][tc]=__builtin_amdgcn_mfma_f32_16x16x32_bf16(ap[tr],bv,ov[tr][tc],0,0,0);
        }
      }
      #pragma unroll
      for(int tr=0;tr<2;++tr){
        #pragma unroll
        for(int tc=0;tc<2;++tc){
          #pragma unroll
          for(int r=0;r<4;++r)
            *(unsigned short*)(sm+SO+swz64(wr*32+tr*16+lg*4+r,(hl*32+tc*16+l16)*2))=f2b(ov[tr][tc][r]);
        }
      }
    }
    __syncthreads();
    // ---- C.4: accP += O_pair @ w_proj[p*64 .. p*64+64, :]  (no barrier after; next C.1 touches other bufs) ----
    #pragma unroll
    for(int ks=0;ks<2;++ks){
      bf16x8 ao[4];
      #pragma unroll
      for(int tr=0;tr<4;++tr) ao[tr]=*(const bf16x8*)(sm+SO+swz64(tr*16+l16, ks*64+lg*16));
      #pragma unroll
      for(int tc=0;tc<3;++tc){
        const bf16x8 bw=*(const bf16x8*)(wprojT + (w*48+tc*16+l16)*192 + p*64+ks*32+lg*8);
        #pragma unroll
        for(int tr=0;tr<4;++tr)
          accP[tr][tc]=__builtin_amdgcn_mfma_f32_16x16x32_bf16(ao[tr],bw,accP[tr][tc],0,0,0);
      }
    }
  } // head pairs

  // ---- Phase D: projout(+bias) -> sA bf16; t += ; LN2 -> sA (h2) ----
  #pragma unroll
  for(int tc=0;tc<3;++tc){
    const float bp=bproj[w*48+tc*16+l16];
    #pragma unroll
    for(int tr=0;tr<4;++tr){
      #pragma unroll
      for(int r=0;r<4;++r)
        *(unsigned short*)(sm+SA+swzA(tr*16+lg*4+r, w*96+tc*32+l16*2))=f2b(accP[tr][tc][r]+bp);
    }
  }
  __syncthreads();
  #pragma unroll
  for(int ch=0;ch<6;++ch){
    const u16x8 pk=*(const u16x8*)(sm+SA+swzA(l, w*96+ch*16));
    #pragma unroll
    for(int j=0;j<8;++j) t[ch*8+j]+=b2f(pk[j]);
  }
  { // LN2 (reads of projout above happen before red-write barrier -> safe to overwrite sA after it)
    float s=0.f,s2=0.f;
    #pragma unroll
    for(int i=0;i<48;++i){ s+=t[i]; s2+=t[i]*t[i]; }
    red[(w*64+l)*2]=s; red[(w*64+l)*2+1]=s2;
    __syncthreads();
    float S=0.f,S2=0.f;
    #pragma unroll
    for(int u=0;u<4;++u){ S+=red[(u*64+l)*2]; S2+=red[(u*64+l)*2+1]; }
    float mean=S*(1.f/192.f), var=S2*(1.f/192.f)-mean*mean, rstd=rsqrtf(var+1e-5f);
    #pragma unroll
    for(int ch=0;ch<6;++ch){
      u16x8 pk;
      #pragma unroll
      for(int j=0;j<8;++j){ int c=w*48+ch*8+j; pk[j]=f2b((t[ch*8+j]-mean)*rstd*ln2g[c]+ln2b[c]); }
      *(u16x8*)(sm+SA+swzA(l, w*96+ch*16))=pk;
    }
    __syncthreads();
  }

  // ---- Phase E: MLP in 4 K-chunks of 192; accM = sum_chunks gelu(h2@W1+b1) @ W2 ----
  f32x4 accM[4][3];
  #pragma unroll
  for(int ii=0;ii<4;++ii){
    #pragma unroll
    for(int jj=0;jj<3;++jj) accM[ii][jj]=(f32x4){0.f,0.f,0.f,0.f};
  }
  #pragma unroll 1
  for(int qc=0;qc<4;++qc){
    f32x4 g[4][3];
    #pragma unroll
    for(int ii=0;ii<4;++ii){
      #pragma unroll
      for(int jj=0;jj<3;++jj) g[ii][jj]=(f32x4){0.f,0.f,0.f,0.f};
    }
    #pragma unroll
    for(int ks=0;ks<6;++ks){
      bf16x8 a[4];
      #pragma unroll
      for(int tr=0;tr<4;++tr) a[tr]=*(const bf16x8*)(sm+SA+swzA(tr*16+l16, ks*64+lg*16));
      #pragma unroll
      for(int tc=0;tc<3;++tc){
        const bf16x8 bw=*(const bf16x8*)(wmlp1T + (qc*192+w*48+tc*16+l16)*192 + ks*32+lg*8);
        #pragma unroll
        for(int tr=0;tr<4;++tr)
          g[tr][tc]=__builtin_amdgcn_mfma_f32_16x16x32_bf16(a[tr],bw,g[tr][tc],0,0,0);
      }
    }
    #pragma unroll
    for(int tc=0;tc<3;++tc){
      const float b1=bmlp1[qc*192+w*48+tc*16+l16];
      #pragma unroll
      for(int tr=0;tr<4;++tr){
        #pragma unroll
        for(int r=0;r<4;++r){
          const float xv=g[tr][tc][r]+b1;
          const float gv=0.5f*xv*(1.f+erff(xv*0.70710678118654752f)); // exact gelu
          *(unsigned short*)(sm+SG+swzA(tr*16+lg*4+r, w*96+tc*32+l16*2))=f2b(gv);
        }
      }
    }
    __syncthreads();
    #pragma unroll
    for(int ks=0;ks<6;++ks){
      bf16x8 a[4];
      #pragma unroll
      for(int tr=0;tr<4;++tr) a[tr]=*(const bf16x8*)(sm+SG+swzA(tr*16+l16, ks*64+lg*16));
      #pragma unroll
      for(int tc=0;tc<3;++tc){
        const bf16x8 bw=*(const bf16x8*)(wmlp2T + (w*48+tc*16+l16)*768 + qc*192+ks*32+lg*8);
        #pragma unroll
        for(int tr=0;tr<4;++tr)
          accM[tr][tc]=__builtin_amdgcn_mfma_f32_16x16x32_bf16(a[tr],bw,accM[tr][tc],0,0,0);
      }
    }
    __syncthreads();
  }

  // ---- Phase F: mlpout(+bias) -> sA; final residual; store to [B][C][H][W] ----
  #pragma unroll
  for(int tc=0;tc<3;++tc){
    const float b2=bmlp2[w*48+tc*16+l16];
    #pragma unroll
    for(int tr=0;tr<4;++tr){
      #pragma unroll
      for(int r=0;r<4;++r)
        *(unsigned short*)(sm+SA+swzA(tr*16+lg*4+r, w*96+tc*32+l16*2))=f2b(accM[tr][tc][r]+b2);
    }
  }
  __syncthreads();
  #pragma unroll
  for(int ch=0;ch<6;++ch){
    const u16x8 pk=*(const u16x8*)(sm+SA+swzA(l, w*96+ch*16));
    #pragma unroll
    for(int j=0;j<8;++j)
      out[imgoff+(size_t)(w*48+ch*8+j)*65536+(size_t)toff]=t[ch*8+j]+b2f(pk[j]);
  }
}

extern "C" void kernel_launch(void* const* d_in, const int* in_sizes, int n_in,
                              void* d_out, int out_size, void* d_ws, size_t ws_size,
                              hipStream_t stream) {
  const float* x      = (const float*)d_in[0];
  const float* w_qkv  = (const float*)d_in[1];
  const float* b_qkv  = (const float*)d_in[2];
  const float* w_proj = (const float*)d_in[3];
  const float* b_proj = (const float*)d_in[4];
  const float* ln1g   = (const float*)d_in[5];
  const float* ln1b   = (const float*)d_in[6];
  const float* ln2g   = (const float*)d_in[7];
  const float* ln2b   = (const float*)d_in[8];
  const float* w_mlp1 = (const float*)d_in[9];
  const float* b_mlp1 = (const float*)d_in[10];
  const float* w_mlp2 = (const float*)d_in[11];
  const float* b_mlp2 = (const float*)d_in[12];
  unsigned short* wsu = (unsigned short*)d_ws;

  prep_weights<<<dim3(1728), dim3(256), 0, stream>>>(w_qkv, w_proj, w_mlp1, w_mlp2, wsu);
  winblock<<<dim3(4096), dim3(256), 0, stream>>>(
      x, b_qkv, b_proj, ln1g, ln1b, ln2g, ln2b, b_mlp1, b_mlp2,
      wsu, wsu+110592, wsu+147456, wsu+294912, (float*)d_out);
}